// Round 1
// baseline (266.930 us; speedup 1.0000x reference)
//
#include <hip/hip_runtime.h>
#include <hip/hip_bf16.h>
#include <math.h>

#define B_  16
#define C_  64
#define H_  128
#define W_  128
#define HW_ (H_ * W_)
#define CR_ 4
#define K9C (9 * C_)   // 576
#define SEC 16
#define TW  130        // transposed buffer spatial dim (128 + 2 halo)
#define XPAD 72        // LDS pixel stride in elements for k_se1 (64 + 8 pad)

typedef float f32x4 __attribute__((ext_vector_type(4)));
typedef __bf16 bf16x8 __attribute__((ext_vector_type(8)));

static __device__ __forceinline__ unsigned short f2us(float f) {
    __bf16 h = (__bf16)f;
    return __builtin_bit_cast(unsigned short, h);
}

// ---------------------------------------------------------------------------
// K2: x (NCHW fp32) -> t (b, y', x', c) bf16 with zeroed 1-px halo border.
// Also accumulates per-(b,c) sums into y0 (atomic), replacing the old k_mean.
// grid = B*H blocks (one row each), 256 threads.
__global__ void k_tr(const float* __restrict__ x, unsigned short* __restrict__ t,
                     float* __restrict__ y0) {
    int blk = blockIdx.x;
    int b = blk >> 7, y = blk & 127;
    __shared__ unsigned short lds[C_ * TW];   // [c][x], x-stride 130 (2-way banks)
    int tid = threadIdx.x;
    // phase 1: coalesced read of 64 channel-rows, convert to bf16 into LDS.
    // fused mean: 32-lane groups share channel c -> shuffle-reduce + atomic.
    for (int i = tid; i < C_ * 32; i += 256) {
        int c = i >> 5, xq = i & 31;
        float4 v = *(const float4*)(x + (((size_t)(b * C_ + c)) << 14) + (y << 7) + (xq << 2));
        unsigned int p0 = f2us(v.x) | ((unsigned int)f2us(v.y) << 16);
        unsigned int p1 = f2us(v.z) | ((unsigned int)f2us(v.w) << 16);
        *(unsigned int*)&lds[c * TW + (xq << 2)]     = p0;
        *(unsigned int*)&lds[c * TW + (xq << 2) + 2] = p1;
        float s4 = v.x + v.y + v.z + v.w;
        s4 += __shfl_down(s4, 16, 32);
        s4 += __shfl_down(s4, 8, 32);
        s4 += __shfl_down(s4, 4, 32);
        s4 += __shfl_down(s4, 2, 32);
        s4 += __shfl_down(s4, 1, 32);
        if ((tid & 31) == 0) atomicAdd(&y0[b * C_ + c], s4);
    }
    __syncthreads();
    // phase 2: transpose to pixel-major, channel-minor; write row y+1 of t
    size_t rowbase = ((size_t)(b * TW + y + 1)) * TW * C_;
    for (int j = tid; j < 128 * 16; j += 256) {
        int px = j >> 4, g = j & 15;
        unsigned short a0 = lds[(4 * g + 0) * TW + px];
        unsigned short a1 = lds[(4 * g + 1) * TW + px];
        unsigned short a2 = lds[(4 * g + 2) * TW + px];
        unsigned short a3 = lds[(4 * g + 3) * TW + px];
        uint2 wv;
        wv.x = a0 | ((unsigned int)a1 << 16);
        wv.y = a2 | ((unsigned int)a3 << 16);
        *(uint2*)(t + rowbase + (size_t)(px + 1) * C_ + (g << 2)) = wv;
    }
    // halo: zero columns x'=0 and x'=129 of this row
    if (tid < 16) {
        int px = (tid < 8) ? 0 : (TW - 1);
        int ch = tid & 7;
        uint4 z = {0, 0, 0, 0};
        *(uint4*)(t + rowbase + (size_t)px * C_ + ch * 8) = z;
    }
    // halo: zero full rows y'=0 / y'=129
    if (y == 0) {
        size_t base = (size_t)b * TW * TW * C_;
        uint4 z = {0, 0, 0, 0};
        for (int i = tid; i < TW * C_ / 8; i += 256)
            *(uint4*)(t + base + (size_t)i * 8) = z;
    }
    if (y == 127) {
        size_t base = ((size_t)(b * TW + TW - 1)) * TW * C_;
        uint4 z = {0, 0, 0, 0};
        for (int i = tid; i < TW * C_ / 8; i += 256)
            *(uint4*)(t + base + (size_t)i * 8) = z;
    }
}

// ---------------------------------------------------------------------------
// K3: transpose se_w1 [16][64][9] -> w1t [tap][o][c] bf16. Also zeroes y0
// (must run before k_tr's atomic accumulation; stream order guarantees it).
__global__ void k_w1t(const float* __restrict__ se_w1, unsigned short* __restrict__ w1t,
                      float* __restrict__ y0) {
    if (blockIdx.x < 4) y0[(blockIdx.x << 8) | threadIdx.x] = 0.f;
    int idx = blockIdx.x * 256 + threadIdx.x;   // < 9*16*64 = 9216
    int tap = idx >> 10, o = (idx >> 6) & 15, c = idx & 63;
    w1t[idx] = f2us(se_w1[(o * C_ + c) * 9 + tap]);
}

// ---------------------------------------------------------------------------
// K4a: channel attention vector only: y0(sums) -> FC1+relu -> FC2+sigmoid
// sy[b][576] fp32. grid = B.
__global__ void k_att(const float* __restrict__ y0,
                      const float* __restrict__ fc_w1,
                      const float* __restrict__ fc_w2,
                      float* __restrict__ sy) {
    int b = blockIdx.x;
    int t = threadIdx.x;
    __shared__ float sy0[C_];
    __shared__ float sh[CR_];
    if (t < C_) sy0[t] = y0[b * C_ + t] * (1.0f / (float)HW_);
    __syncthreads();
    if (t < CR_) {
        float s = 0.f;
        for (int c = 0; c < C_; ++c) s = fmaf(fc_w1[t * C_ + c], sy0[c], s);
        sh[t] = fmaxf(s, 0.f);
    }
    __syncthreads();
    for (int i = t; i < K9C; i += 256) {
        float s = 0.f;
        #pragma unroll
        for (int j = 0; j < CR_; ++j) s = fmaf(fc_w2[i * CR_ + j], sh[j], s);
        sy[b * K9C + i] = 1.f / (1.f + expf(-s));
    }
}

// ---------------------------------------------------------------------------
// K4b: build w_t in MFMA-fragment order:
//   w_t[b][tap][mt][half][lane][e] = weight[o][c][tap] * sy[b][c*9+tap]
//   with o = mt*16 + (lane&15), c = half*32 + (lane>>4)*8 + e.
// A wave in k_main then loads its A-fragment as ONE contiguous 1KB block.
// grid = B*4 (one mt each), 256 threads.
__global__ void k_wt(const float* __restrict__ sy, const float* __restrict__ weight,
                     unsigned short* __restrict__ w_t) {
    int blk = blockIdx.x;
    int b = blk >> 2, mt = blk & 3;
    __shared__ float ssy[K9C];
    __shared__ float sw[16 * 576];   // weight rows o = mt*16 .. mt*16+15
    int tid = threadIdx.x;
    for (int i = tid; i < K9C; i += 256) ssy[i] = sy[b * K9C + i];
    const float* wsrc = weight + (size_t)(mt * 16) * 576;
    for (int i = tid; i < 16 * 576; i += 256) sw[i] = wsrc[i];
    __syncthreads();
    unsigned short* wb = w_t + (size_t)b * 9 * C_ * C_;
    for (int ii = tid; ii < 4608; ii += 256) {
        int i = ii << 1;                      // pair of elements e, e+1 (e even)
        int tap = i >> 10, r = i & 1023;
        int half = r >> 9, lane = (r >> 3) & 63, e = r & 7;
        int o = lane & 15;
        int c = half * 32 + ((lane >> 4) << 3) + e;
        float v0 = sw[o * 576 + c * 9 + tap] * ssy[c * 9 + tap];
        float v1 = sw[o * 576 + (c + 1) * 9 + tap] * ssy[(c + 1) * 9 + tap];
        unsigned int pk = f2us(v0) | ((unsigned int)f2us(v1) << 16);
        *(unsigned int*)(wb + ((tap * 4 + mt) * 2 + half) * 512 + lane * 8 + e) = pk;
    }
}

// ---------------------------------------------------------------------------
// K5: SE conv1 via MFMA (M=16, K=64 per tap, N=pixels) + relu -> mid NHWC bf16
__global__ void __launch_bounds__(256, 3)
k_se1(const unsigned short* __restrict__ t, const unsigned short* __restrict__ w1t,
      unsigned short* __restrict__ mid) {
    int blk = blockIdx.x;
    int b = blk >> 6, tile = blk & 63;
    int ty0 = (tile >> 3) << 4, tx0 = (tile & 7) << 4;
    int tid = threadIdx.x, lane = tid & 63, wave = tid >> 6;
    int n = lane & 15, q = lane >> 4, qc = q << 3;
    __shared__ __align__(16) unsigned short xt[18 * 18 * XPAD];
    const unsigned short* tb = t + ((size_t)b * TW + ty0) * TW * C_ + (size_t)tx0 * C_;
    for (int i = tid; i < 18 * 18 * 8; i += 256) {
        int row = i / 144, r = i % 144, px = r >> 3, ch = r & 7;
        uint4 v = *(const uint4*)(tb + ((size_t)row * TW + px) * C_ + ch * 8);
        *(uint4*)&xt[(row * 18 + px) * XPAD + ch * 8] = v;
    }
    __syncthreads();
    f32x4 acc[4] = {};
    #pragma unroll
    for (int tap = 0; tap < 9; ++tap) {
        int ki = tap / 3, kj = tap % 3;
        int xl = n + kj;
        #pragma unroll
        for (int half = 0; half < 2; ++half) {
            int c0 = half << 5;
            uint4 au = *(const uint4*)(w1t + (tap * 16 + n) * C_ + c0 + qc);
            bf16x8 af = __builtin_bit_cast(bf16x8, au);
            #pragma unroll
            for (int j = 0; j < 4; ++j) {
                int yl = 4 * wave + j + ki;
                bf16x8 bf = *(const bf16x8*)&xt[(yl * 18 + xl) * XPAD + c0 + qc];
                acc[j] = __builtin_amdgcn_mfma_f32_16x16x32_bf16(af, bf, acc[j], 0, 0, 0);
            }
        }
    }
    #pragma unroll
    for (int j = 0; j < 4; ++j) {
        int y = ty0 + 4 * wave + j, xx = tx0 + n;
        uint2 wv;
        float v0 = fmaxf(acc[j][0], 0.f), v1 = fmaxf(acc[j][1], 0.f);
        float v2 = fmaxf(acc[j][2], 0.f), v3 = fmaxf(acc[j][3], 0.f);
        wv.x = f2us(v0) | ((unsigned int)f2us(v1) << 16);
        wv.y = f2us(v2) | ((unsigned int)f2us(v3) << 16);
        *(uint2*)(mid + (((size_t)(b << 14) + (y << 7) + xx) << 4) + (q << 2)) = wv;
    }
}

// ---------------------------------------------------------------------------
// K6: SE conv2 (16->1) + sigmoid -> A[b,HW] fp32
__global__ void k_se2(const unsigned short* __restrict__ mid,
                      const float* __restrict__ se_w2,
                      float* __restrict__ A) {
    int idx = blockIdx.x * 256 + threadIdx.x;
    int b = idx >> 14, l = idx & (HW_ - 1);
    int y = l >> 7, xx = l & 127;
    const unsigned short* mb = mid + (((size_t)b) << 14) * 16;
    float s = 0.f;
    #pragma unroll
    for (int ki = 0; ki < 3; ++ki) {
        int yy = y + ki - 1;
        if (yy < 0 || yy >= H_) continue;
        #pragma unroll
        for (int kj = 0; kj < 3; ++kj) {
            int x2 = xx + kj - 1;
            if (x2 < 0 || x2 >= W_) continue;
            const unsigned short* pp = mb + (((size_t)(yy << 7) + x2) << 4);
            bf16x8 v0 = *(const bf16x8*)pp;
            bf16x8 v1 = *(const bf16x8*)(pp + 8);
            #pragma unroll
            for (int e = 0; e < 8; ++e) {
                s = fmaf((float)v0[e], se_w2[e * 9 + ki * 3 + kj], s);
                s = fmaf((float)v1[e], se_w2[(e + 8) * 9 + ki * 3 + kj], s);
            }
        }
    }
    A[idx] = 1.f / (1.f + expf(-s));
}

// ---------------------------------------------------------------------------
// K7: main conv via MFMA. 32x16 px tile, 512 threads (8 waves = 4 wy x 2 wx),
// 2 blocks/CU (78336 B LDS, XOR-swizzled -> no padding, no bank conflicts),
// full 128-B-line fp32 writes (32-wide x). Grid = B*32 = 512 = exactly 2/CU.
// Per wave: 4 m-tiles x 4 rows = 16 accumulators; A-fragments read as
// contiguous 1KB/wave from the fragment-ordered w_t.
__global__ void __launch_bounds__(512, 4)
k_main(const unsigned short* __restrict__ t, const unsigned short* __restrict__ w_t,
       const float* __restrict__ A, float* __restrict__ out) {
    int blk = blockIdx.x;
    int b = blk >> 5, tile = blk & 31;
    int ty0 = (tile >> 2) << 4, tx0 = (tile & 3) << 5;
    int tid = threadIdx.x, lane = tid & 63, wave = tid >> 6;
    int wy = wave >> 1, wx = wave & 1;
    int n = lane & 15, q = lane >> 4;
    __shared__ __align__(16) unsigned short xt[18 * 34 * C_];   // 78336 B, swizzled
    // stage 18x34 pixel tile (all 64 channels); swizzle: 16B chunk ch of pixel
    // px lands at slot ch^(px&7) within the pixel's 128B row.
    const unsigned short* tb = t + ((size_t)b * TW + ty0) * TW * C_ + (size_t)tx0 * C_;
    for (int i = tid; i < 18 * 34 * 8; i += 512) {
        int row = i / 272, r = i % 272, px = r >> 3, ch = r & 7;
        uint4 v = *(const uint4*)(tb + ((size_t)row * TW + px) * C_ + ch * 8);
        *(uint4*)((char*)xt + (row * 34 + px) * 128 + ((ch ^ (px & 7)) << 4)) = v;
    }
    __syncthreads();
    f32x4 acc[4][4] = {};   // [m-tile][row j]
    const unsigned short* wb = w_t + (size_t)b * 9 * C_ * C_;
    #pragma unroll
    for (int tap = 0; tap < 9; ++tap) {
        int ki = tap / 3, kj = tap % 3;
        int xl = wx * 16 + n + kj;
        int xk = xl & 7;
        #pragma unroll
        for (int half = 0; half < 2; ++half) {
            bf16x8 af[4];
            #pragma unroll
            for (int mt = 0; mt < 4; ++mt) {
                uint4 au = *(const uint4*)(wb + (((tap * 4 + mt) * 2 + half) << 9) + (lane << 3));
                af[mt] = __builtin_bit_cast(bf16x8, au);
            }
            int slot = (((half << 2) + q) ^ xk) << 4;
            #pragma unroll
            for (int j = 0; j < 4; ++j) {
                int yl = 4 * wy + j + ki;
                bf16x8 bf = *(const bf16x8*)((const char*)xt + (yl * 34 + xl) * 128 + slot);
                #pragma unroll
                for (int mt = 0; mt < 4; ++mt)
                    acc[mt][j] = __builtin_amdgcn_mfma_f32_16x16x32_bf16(af[mt], bf, acc[mt][j], 0, 0, 0);
            }
        }
    }
    // epilogue: scale by A, store NCHW fp32 (sibling wx waves complete each line)
    #pragma unroll
    for (int j = 0; j < 4; ++j) {
        int y = ty0 + 4 * wy + j, xx = tx0 + (wx << 4) + n;
        float a = A[(b << 14) + (y << 7) + xx];
        #pragma unroll
        for (int mt = 0; mt < 4; ++mt) {
            #pragma unroll
            for (int r = 0; r < 4; ++r) {
                int o = (mt << 4) + (q << 2) + r;
                out[(((size_t)(b * C_ + o)) << 14) + (y << 7) + xx] = acc[mt][j][r] * a;
            }
        }
    }
}

// ---------------------------------------------------------------------------
extern "C" void kernel_launch(void* const* d_in, const int* in_sizes, int n_in,
                              void* d_out, int out_size, void* d_ws, size_t ws_size,
                              hipStream_t stream) {
    const float* x      = (const float*)d_in[0];
    const float* weight = (const float*)d_in[1];
    const float* se_w1  = (const float*)d_in[2];
    const float* se_w2  = (const float*)d_in[3];
    const float* fc_w1  = (const float*)d_in[4];
    const float* fc_w2  = (const float*)d_in[5];
    float* out = (float*)d_out;

    char* ws = (char*)d_ws;
    float* y0            = (float*)ws;                         ws += 4096;
    float* sy            = (float*)ws;                         ws += (size_t)B_ * K9C * 4;
    float* A             = (float*)ws;                         ws += (size_t)B_ * HW_ * 4;
    unsigned short* t    = (unsigned short*)ws;                ws += (size_t)B_ * TW * TW * C_ * 2 + 4096;
    unsigned short* w_t  = (unsigned short*)ws;                ws += (size_t)B_ * 9 * C_ * C_ * 2;
    unsigned short* w1t  = (unsigned short*)ws;                ws += 9 * 16 * C_ * 2;
    unsigned short* mid  = (unsigned short*)ws;

    k_w1t<<<36, 256, 0, stream>>>(se_w1, w1t, y0);            // zeroes y0 first
    k_tr  <<<B_ * H_, 256, 0, stream>>>(x, t, y0);            // + fused mean
    k_att <<<B_, 256, 0, stream>>>(y0, fc_w1, fc_w2, sy);
    k_wt  <<<B_ * 4, 256, 0, stream>>>(sy, weight, w_t);
    k_se1 <<<B_ * 64, 256, 0, stream>>>(t, w1t, mid);
    k_se2 <<<B_ * HW_ / 256, 256, 0, stream>>>(mid, se_w2, A);
    k_main<<<B_ * 32, 512, 0, stream>>>(t, w_t, A, out);
}

// Round 2
// 229.133 us; speedup vs baseline: 1.1650x; 1.1650x over previous
//
#include <hip/hip_runtime.h>
#include <hip/hip_bf16.h>
#include <math.h>

#define B_  16
#define C_  64
#define H_  128
#define W_  128
#define HW_ (H_ * W_)
#define CR_ 4
#define K9C (9 * C_)   // 576
#define TW  130        // transposed buffer spatial dim (128 + 2 halo)

typedef float f32x4 __attribute__((ext_vector_type(4)));
typedef __bf16 bf16x8 __attribute__((ext_vector_type(8)));

static __device__ __forceinline__ unsigned short f2us(float f) {
    __bf16 h = (__bf16)f;
    return __builtin_bit_cast(unsigned short, h);
}

// ---------------------------------------------------------------------------
// K2: x (NCHW fp32) -> t (b, y', x', c) bf16 with zeroed 1-px halo border.
// Also accumulates per-(b,c) sums into y0 (atomic), replacing a k_mean pass.
__global__ void k_tr(const float* __restrict__ x, unsigned short* __restrict__ t,
                     float* __restrict__ y0) {
    int blk = blockIdx.x;
    int b = blk >> 7, y = blk & 127;
    __shared__ unsigned short lds[C_ * TW];
    int tid = threadIdx.x;
    for (int i = tid; i < C_ * 32; i += 256) {
        int c = i >> 5, xq = i & 31;
        float4 v = *(const float4*)(x + (((size_t)(b * C_ + c)) << 14) + (y << 7) + (xq << 2));
        unsigned int p0 = f2us(v.x) | ((unsigned int)f2us(v.y) << 16);
        unsigned int p1 = f2us(v.z) | ((unsigned int)f2us(v.w) << 16);
        *(unsigned int*)&lds[c * TW + (xq << 2)]     = p0;
        *(unsigned int*)&lds[c * TW + (xq << 2) + 2] = p1;
        float s4 = v.x + v.y + v.z + v.w;
        s4 += __shfl_down(s4, 16, 32);
        s4 += __shfl_down(s4, 8, 32);
        s4 += __shfl_down(s4, 4, 32);
        s4 += __shfl_down(s4, 2, 32);
        s4 += __shfl_down(s4, 1, 32);
        if ((tid & 31) == 0) atomicAdd(&y0[b * C_ + c], s4);
    }
    __syncthreads();
    size_t rowbase = ((size_t)(b * TW + y + 1)) * TW * C_;
    for (int j = tid; j < 128 * 16; j += 256) {
        int px = j >> 4, g = j & 15;
        unsigned short a0 = lds[(4 * g + 0) * TW + px];
        unsigned short a1 = lds[(4 * g + 1) * TW + px];
        unsigned short a2 = lds[(4 * g + 2) * TW + px];
        unsigned short a3 = lds[(4 * g + 3) * TW + px];
        uint2 wv;
        wv.x = a0 | ((unsigned int)a1 << 16);
        wv.y = a2 | ((unsigned int)a3 << 16);
        *(uint2*)(t + rowbase + (size_t)(px + 1) * C_ + (g << 2)) = wv;
    }
    if (tid < 16) {
        int px = (tid < 8) ? 0 : (TW - 1);
        int ch = tid & 7;
        uint4 z = {0, 0, 0, 0};
        *(uint4*)(t + rowbase + (size_t)px * C_ + ch * 8) = z;
    }
    if (y == 0) {
        size_t base = (size_t)b * TW * TW * C_;
        uint4 z = {0, 0, 0, 0};
        for (int i = tid; i < TW * C_ / 8; i += 256)
            *(uint4*)(t + base + (size_t)i * 8) = z;
    }
    if (y == 127) {
        size_t base = ((size_t)(b * TW + TW - 1)) * TW * C_;
        uint4 z = {0, 0, 0, 0};
        for (int i = tid; i < TW * C_ / 8; i += 256)
            *(uint4*)(t + base + (size_t)i * 8) = z;
    }
}

// ---------------------------------------------------------------------------
// K3: transpose se_w1 [16][64][9] -> w1t [tap][o][c] bf16. Also zeroes y0.
__global__ void k_w1t(const float* __restrict__ se_w1, unsigned short* __restrict__ w1t,
                      float* __restrict__ y0) {
    if (blockIdx.x < 4) y0[(blockIdx.x << 8) | threadIdx.x] = 0.f;
    int idx = blockIdx.x * 256 + threadIdx.x;
    int tap = idx >> 10, o = (idx >> 6) & 15, c = idx & 63;
    w1t[idx] = f2us(se_w1[(o * C_ + c) * 9 + tap]);
}

// ---------------------------------------------------------------------------
// K4a: channel attention vector: y0(sums) -> FC1+relu -> FC2+sigmoid
__global__ void k_att(const float* __restrict__ y0,
                      const float* __restrict__ fc_w1,
                      const float* __restrict__ fc_w2,
                      float* __restrict__ sy) {
    int b = blockIdx.x;
    int t = threadIdx.x;
    __shared__ float sy0[C_];
    __shared__ float sh[CR_];
    if (t < C_) sy0[t] = y0[b * C_ + t] * (1.0f / (float)HW_);
    __syncthreads();
    if (t < CR_) {
        float s = 0.f;
        for (int c = 0; c < C_; ++c) s = fmaf(fc_w1[t * C_ + c], sy0[c], s);
        sh[t] = fmaxf(s, 0.f);
    }
    __syncthreads();
    for (int i = t; i < K9C; i += 256) {
        float s = 0.f;
        #pragma unroll
        for (int j = 0; j < CR_; ++j) s = fmaf(fc_w2[i * CR_ + j], sh[j], s);
        sy[b * K9C + i] = 1.f / (1.f + expf(-s));
    }
}

// ---------------------------------------------------------------------------
// K4b: build w_t in MFMA-fragment order (verified in prev round).
__global__ void k_wt(const float* __restrict__ sy, const float* __restrict__ weight,
                     unsigned short* __restrict__ w_t) {
    int blk = blockIdx.x;
    int b = blk >> 2, mt = blk & 3;
    __shared__ float ssy[K9C];
    __shared__ float sw[16 * 576];
    int tid = threadIdx.x;
    for (int i = tid; i < K9C; i += 256) ssy[i] = sy[b * K9C + i];
    const float* wsrc = weight + (size_t)(mt * 16) * 576;
    for (int i = tid; i < 16 * 576; i += 256) sw[i] = wsrc[i];
    __syncthreads();
    unsigned short* wb = w_t + (size_t)b * 9 * C_ * C_;
    for (int ii = tid; ii < 4608; ii += 256) {
        int i = ii << 1;
        int tap = i >> 10, r = i & 1023;
        int half = r >> 9, lane = (r >> 3) & 63, e = r & 7;
        int o = lane & 15;
        int c = half * 32 + ((lane >> 4) << 3) + e;
        float v0 = sw[o * 576 + c * 9 + tap] * ssy[c * 9 + tap];
        float v1 = sw[o * 576 + (c + 1) * 9 + tap] * ssy[(c + 1) * 9 + tap];
        unsigned int pk = f2us(v0) | ((unsigned int)f2us(v1) << 16);
        *(unsigned int*)(wb + ((tap * 4 + mt) * 2 + half) * 512 + lane * 8 + e) = pk;
    }
}

// ---------------------------------------------------------------------------
// K5: FUSED SE: conv1(3x3,64->16)+relu -> LDS mid(18x18) -> conv2(3x3,16->1)
// + sigmoid -> A. mid never touches HBM. Zero-masked outside image = conv2's
// zero padding. grid = B*64 (16x16 A-tiles), 256 threads, 2 blocks/CU.
__global__ void __launch_bounds__(256, 2)
k_se(const unsigned short* __restrict__ t, const unsigned short* __restrict__ w1t,
     const float* __restrict__ se_w2, float* __restrict__ A) {
    int blk = blockIdx.x;
    int b = blk >> 6, tile = blk & 63;
    int ty0 = (tile >> 3) << 4, tx0 = (tile & 7) << 4;
    int tid = threadIdx.x, lane = tid & 63, wave = tid >> 6;
    int n = lane & 15, q = lane >> 4, qc = q << 3;
    __shared__ __align__(16) char xsm[20 * 20 * 128];       // 51200 B, swizzled
    __shared__ __align__(16) unsigned short ms[324 * 16];   // 10368 B mid tile
    // stage x: 20x20 pixels = t rows/cols (ty0-1..ty0+18, tx0-1..tx0+18),
    // zero-fill outside t (only used by masked mid rows).
    const unsigned short* tb = t + (size_t)b * TW * TW * C_;
    for (int i = tid; i < 20 * 20 * 8; i += 256) {
        int row = i / 160, r = i % 160, px = r >> 3, ch = r & 7;
        int tr = ty0 - 1 + row, tc = tx0 - 1 + px;
        uint4 v = {0, 0, 0, 0};
        if (tr >= 0 && tr < TW && tc >= 0 && tc < TW)
            v = *(const uint4*)(tb + ((size_t)tr * TW + tc) * C_ + ch * 8);
        *(uint4*)(xsm + (row * 20 + px) * 128 + ((ch ^ (px & 7)) << 4)) = v;
    }
    __syncthreads();
    // conv1 over 324 mid pixels as flat-N 16-px MFMA groups; group g handled
    // by wave g&3 (wave-uniform skip for g>=21).
    int prow[6], pcol[6];
    #pragma unroll
    for (int i = 0; i < 6; ++i) {
        int g = wave + 4 * i;
        int p = g * 16 + n; if (p > 323) p = 323;
        prow[i] = p / 18; pcol[i] = p % 18;
    }
    f32x4 acc[6] = {};
    #pragma unroll
    for (int tap = 0; tap < 9; ++tap) {
        int ki = tap / 3, kj = tap % 3;
        uint4 a0 = *(const uint4*)(w1t + (tap * 16 + n) * C_ + qc);
        uint4 a1 = *(const uint4*)(w1t + (tap * 16 + n) * C_ + 32 + qc);
        bf16x8 af0 = __builtin_bit_cast(bf16x8, a0);
        bf16x8 af1 = __builtin_bit_cast(bf16x8, a1);
        #pragma unroll
        for (int i = 0; i < 6; ++i) {
            int g = wave + 4 * i;
            if (g < 21) {
                int xr = prow[i] + ki, xc = pcol[i] + kj;
                int base = (xr * 20 + xc) * 128;
                bf16x8 b0 = *(const bf16x8*)(xsm + base + (((0 + q) ^ (xc & 7)) << 4));
                bf16x8 b1 = *(const bf16x8*)(xsm + base + (((4 + q) ^ (xc & 7)) << 4));
                acc[i] = __builtin_amdgcn_mfma_f32_16x16x32_bf16(af0, b0, acc[i], 0, 0, 0);
                acc[i] = __builtin_amdgcn_mfma_f32_16x16x32_bf16(af1, b1, acc[i], 0, 0, 0);
            }
        }
    }
    // relu + border mask -> mid in LDS (bf16, 16 ch per pixel)
    #pragma unroll
    for (int i = 0; i < 6; ++i) {
        int g = wave + 4 * i;
        int p = g * 16 + n;
        if (g < 21 && p < 324) {
            int my = ty0 - 1 + prow[i], mx = tx0 - 1 + pcol[i];
            bool valid = (my >= 0) && (my < 128) && (mx >= 0) && (mx < 128);
            float v0 = valid ? fmaxf(acc[i][0], 0.f) : 0.f;
            float v1 = valid ? fmaxf(acc[i][1], 0.f) : 0.f;
            float v2 = valid ? fmaxf(acc[i][2], 0.f) : 0.f;
            float v3 = valid ? fmaxf(acc[i][3], 0.f) : 0.f;
            uint2 wv;
            wv.x = f2us(v0) | ((unsigned int)f2us(v1) << 16);
            wv.y = f2us(v2) | ((unsigned int)f2us(v3) << 16);
            *(uint2*)&ms[p * 16 + (q << 2)] = wv;
        }
    }
    __syncthreads();
    // conv2 + sigmoid: one thread per A-pixel
    int arow = tid >> 4, acol = tid & 15;
    float s = 0.f;
    #pragma unroll
    for (int di = 0; di < 3; ++di) {
        #pragma unroll
        for (int dj = 0; dj < 3; ++dj) {
            const unsigned short* pp = &ms[((arow + di) * 18 + acol + dj) * 16];
            bf16x8 v0 = *(const bf16x8*)pp;
            bf16x8 v1 = *(const bf16x8*)(pp + 8);
            #pragma unroll
            for (int e = 0; e < 8; ++e) {
                s = fmaf((float)v0[e], se_w2[e * 9 + di * 3 + dj], s);
                s = fmaf((float)v1[e], se_w2[(e + 8) * 9 + di * 3 + dj], s);
            }
        }
    }
    A[(b << 14) + ((ty0 + arow) << 7) + tx0 + acol] = 1.f / (1.f + expf(-s));
}

// ---------------------------------------------------------------------------
// K7: main conv via MFMA. 8x32 px tile, 256 threads (4 waves = 2wy x 2wx),
// launch_bounds(256,3) -> 170-reg cap, NO spill (acc 64 + ~84 arch = 148).
// LDS 43520 B swizzled -> 3 blocks/CU. Epilogue transposes through LDS so
// every store instruction writes 8 full 128-B lines (no write-amp, no RMW).
__global__ void __launch_bounds__(256, 3)
k_main(const unsigned short* __restrict__ t, const unsigned short* __restrict__ w_t,
       const float* __restrict__ A, float* __restrict__ out) {
    int blk = blockIdx.x;
    int b = blk >> 6, tile = blk & 63;
    int ty0 = (tile >> 2) << 3, tx0 = (tile & 3) << 5;
    int tid = threadIdx.x, lane = tid & 63, wave = tid >> 6;
    int wy = wave >> 1, wx = wave & 1;
    int n = lane & 15, q = lane >> 4;
    __shared__ __align__(16) char smem[10 * 34 * 128];   // 43520 B
    float* fb = (float*)smem;                            // epilogue reuse [128][32]
    const unsigned short* tb = t + ((size_t)b * TW + ty0) * TW * C_ + (size_t)tx0 * C_;
    for (int i = tid; i < 10 * 34 * 8; i += 256) {
        int row = i / 272, r = i % 272, px = r >> 3, ch = r & 7;
        uint4 v = *(const uint4*)(tb + ((size_t)row * TW + px) * C_ + ch * 8);
        *(uint4*)(smem + (row * 34 + px) * 128 + ((ch ^ (px & 7)) << 4)) = v;
    }
    __syncthreads();
    f32x4 acc[4][4] = {};   // [m-tile][row j]
    const unsigned short* wb = w_t + (size_t)b * 9 * C_ * C_;
    #pragma unroll
    for (int tap = 0; tap < 9; ++tap) {
        int ki = tap / 3, kj = tap % 3;
        int xl = (wx << 4) + n + kj;
        int xk = xl & 7;
        #pragma unroll
        for (int half = 0; half < 2; ++half) {
            bf16x8 af[4];
            #pragma unroll
            for (int mt = 0; mt < 4; ++mt) {
                uint4 au = *(const uint4*)(wb + (((tap * 4 + mt) * 2 + half) << 9) + (lane << 3));
                af[mt] = __builtin_bit_cast(bf16x8, au);
            }
            int slot = (((half << 2) + q) ^ xk) << 4;
            #pragma unroll
            for (int j = 0; j < 4; ++j) {
                int yl = (wy << 2) + j + ki;
                bf16x8 bf = *(const bf16x8*)(smem + (yl * 34 + xl) * 128 + slot);
                #pragma unroll
                for (int mt = 0; mt < 4; ++mt)
                    acc[mt][j] = __builtin_amdgcn_mfma_f32_16x16x32_bf16(af[mt], bf, acc[mt][j], 0, 0, 0);
            }
        }
    }
    // epilogue: per j-row, A-scale -> LDS transpose -> full-line dwordx4 stores
    int xx = tx0 + (wx << 4) + n;
    #pragma unroll
    for (int j = 0; j < 4; ++j) {
        __syncthreads();   // j=0: xt reads done; j>0: prev readback done
        int y = ty0 + (wy << 2) + j;
        float a = A[(b << 14) + (y << 7) + xx];
        #pragma unroll
        for (int mt = 0; mt < 4; ++mt) {
            #pragma unroll
            for (int r = 0; r < 4; ++r) {
                int o = (mt << 4) + (q << 2) + r;
                fb[(((wy << 6) + o) << 5) + (wx << 4) + n] = acc[mt][j][r] * a;
            }
        }
        __syncthreads();
        #pragma unroll
        for (int it = 0; it < 4; ++it) {
            int s = it * 256 + tid;
            int row = s >> 3, xq = s & 7;
            int wy2 = row >> 6, o = row & 63;
            float4 v = *(const float4*)&fb[(row << 5) + (xq << 2)];
            *(float4*)(out + (((size_t)(b * C_ + o)) << 14) +
                       ((ty0 + (wy2 << 2) + j) << 7) + tx0 + (xq << 2)) = v;
        }
    }
}

// ---------------------------------------------------------------------------
extern "C" void kernel_launch(void* const* d_in, const int* in_sizes, int n_in,
                              void* d_out, int out_size, void* d_ws, size_t ws_size,
                              hipStream_t stream) {
    const float* x      = (const float*)d_in[0];
    const float* weight = (const float*)d_in[1];
    const float* se_w1  = (const float*)d_in[2];
    const float* se_w2  = (const float*)d_in[3];
    const float* fc_w1  = (const float*)d_in[4];
    const float* fc_w2  = (const float*)d_in[5];
    float* out = (float*)d_out;

    char* ws = (char*)d_ws;
    float* y0            = (float*)ws;                         ws += 4096;
    float* sy            = (float*)ws;                         ws += (size_t)B_ * K9C * 4;
    float* A             = (float*)ws;                         ws += (size_t)B_ * HW_ * 4;
    unsigned short* t    = (unsigned short*)ws;                ws += (size_t)B_ * TW * TW * C_ * 2 + 4096;
    unsigned short* w_t  = (unsigned short*)ws;                ws += (size_t)B_ * 9 * C_ * C_ * 2;
    unsigned short* w1t  = (unsigned short*)ws;

    k_w1t<<<36, 256, 0, stream>>>(se_w1, w1t, y0);            // zeroes y0 first
    k_tr  <<<B_ * H_, 256, 0, stream>>>(x, t, y0);            // + fused mean
    k_att <<<B_, 256, 0, stream>>>(y0, fc_w1, fc_w2, sy);
    k_wt  <<<B_ * 4, 256, 0, stream>>>(sy, weight, w_t);
    k_se  <<<B_ * 64, 256, 0, stream>>>(t, w1t, se_w2, A);
    k_main<<<B_ * 64, 256, 0, stream>>>(t, w_t, A, out);
}